// Round 7
// baseline (262466.089 us; speedup 1.0000x reference)
//
#include <hip/hip_runtime.h>
#include <hip/hip_cooperative_groups.h>
#include <math.h>

namespace cg = cooperative_groups;

// ---------------- problem constants ----------------
#define TSTEPS 400
#define KSP1 7
#define KSP2 8

// ---------------- workspace layout (float offsets) ----------------
#define OFF_XPRE  0u          // prenet out, BF16 [t][k][b]
#define OFF_PM    1638400u    // tanh(memory@wm) fp32 [b][t][128]
#define OFF_IN1T  2457600u    // lstm1 input rows 256..1791, [(k-256)][b]
#define OFF_IN2T  2506752u    // lstm2 input rows [k][b] (2560x32)
#define OFF_ZP1   2588672u    // coop: z1 [b][4096] | fallback: partials [7][32][4096]
#define OFF_ZP2   3506176u    // coop: z2 [b][4096] | fallback: partials [8][32][4096]
#define OFF_CTXP  4554752u    // ctx 4-deep [t&3][b][512]
#define OFF_H2B   4620288u    // h2 2-deep [parity][k][b]
#define OFF_C1    4685824u
#define OFF_C2    4718592u
#define OFF_ATTW  4751360u
#define OFF_CUM   4757760u
#define WS_FLOATS 4764160u

#define OUT_GATE  1024000
#define OUT_ALIGN 1036800

__device__ __forceinline__ float sigf(float x)   { return 1.f / (1.f + __expf(-x)); }
__device__ __forceinline__ float tanhf_(float x) { return 1.f - 2.f / (__expf(2.f*x) + 1.f); }

// ---------------- prologue kernels ----------------
__global__ void __launch_bounds__(256) prenet_kernel(
    const float* __restrict__ dec, const float* __restrict__ w0, const float* __restrict__ b0,
    const float* __restrict__ w1, const float* __restrict__ b1, float* __restrict__ ws)
{
    __shared__ float s_in[80];
    __shared__ float s_h0[256];
    int t = blockIdx.x, b = blockIdx.y, tid = threadIdx.x;
    if (tid < 80) s_in[tid] = (t == 0) ? 0.f : dec[b*32000 + tid*400 + (t-1)];
    __syncthreads();
    float s = b0[tid];
    for (int m = 0; m < 80; ++m) s = fmaf(s_in[m], w0[m*256 + tid], s);
    s_h0[tid] = fmaxf(s, 0.f);
    __syncthreads();
    float s2 = b1[tid];
    for (int k = 0; k < 256; ++k) s2 = fmaf(s_h0[k], w1[k*256 + tid], s2);
    float v = fmaxf(s2, 0.f);
    unsigned u = __float_as_uint(v);
    u += 0x7fffu + ((u >> 16) & 1u);
    ((unsigned short*)(ws + OFF_XPRE))[(size_t)t*8192 + tid*32 + b] = (unsigned short)(u >> 16);
}

__global__ void __launch_bounds__(128) pmem_kernel(
    const float* __restrict__ mp, const float* __restrict__ wm, float* __restrict__ ws)
{
    int t = blockIdx.x, b = blockIdx.y, a = threadIdx.x;
    const float* mrow = mp + (b*200 + t)*512;
    float s = 0.f;
    for (int d = 0; d < 512; ++d) s = fmaf(mrow[d], wm[d*128 + a], s);
    ws[OFF_PM + (b*200 + t)*128 + a] = tanhf_(s);
}

__global__ void __launch_bounds__(256) zero_kernel(float* __restrict__ ws)
{
    int gid = blockIdx.x*256 + threadIdx.x, gsz = gridDim.x*256;
    for (int i = gid; i < 49152; i += gsz) ws[OFF_IN1T + i] = 0.f;
    for (int i = gid; i < 81920; i += gsz) ws[OFF_IN2T + i] = 0.f;
    for (int i = gid; i < 32768; i += gsz) { ws[OFF_C1 + i] = 0.f; ws[OFF_C2 + i] = 0.f; }
    for (int i = gid; i < 65536; i += gsz) { ws[OFF_CTXP + i] = 0.f; ws[OFF_H2B + i] = 0.f; }
    for (int i = gid; i < 6400;  i += gsz) { ws[OFF_ATTW + i] = 0.f; ws[OFF_CUM + i] = 0.f; }
}

// ================================================================
// Persistent cooperative decoder, weights resident in registers.
// 256 blocks x 512 thr, 1 block/CU, <=256 VGPR (launch_bounds 512,2).
// Thread (jl = tid>>5 in [0,16), kq = tid&31): col = bid*16 + jl,
// k in {kq + 32*i}. w1[56] (gemv1 K=1792) + w2[80] (gemv2 K=2560).
// Per step: PHASE1 all blocks: gemv1(t), gemv2(t-1) from LDS-staged x
//   (chunks of <=896 rows, [row][36] pad), butterfly-reduce over kq,
//   write z1/z2 fully reduced. grid.sync.
// PHASE2: blocks 0-31 attn+gates1(t) | 32-63 gates2(t-1)
//   | 64-103 mel(t-2) | 104 stop(t-2). grid.sync.
// ================================================================
__global__ void __launch_bounds__(512, 2) decoder_kernel(
    const float* __restrict__ mp,
    const float* __restrict__ l1k, const float* __restrict__ l1r, const float* __restrict__ l1b,
    const float* __restrict__ l2k, const float* __restrict__ l2r, const float* __restrict__ l2b,
    const float* __restrict__ wq, const float* __restrict__ vvec,
    const float* __restrict__ lconv, const float* __restrict__ ldense,
    const float* __restrict__ fw, const float* __restrict__ fb,
    const float* __restrict__ sw, const float* __restrict__ sb,
    float* __restrict__ ws, float* __restrict__ out)
{
    cg::grid_group grid = cg::this_grid();
    __shared__ float s_mem[32256];            // 129 KB: x chunks | phase2 scratch
    const int tid = threadIdx.x, bid = blockIdx.x;
    const int jl = tid >> 5, kq = tid & 31;
    const int col = bid*16 + jl;

    float* z1v = ws + OFF_ZP1;                // [b][4096]
    float* z2v = ws + OFF_ZP2;                // [b][4096]
    float* in1m = ws + OFF_IN1T - 8192;       // valid for k >= 256
    float* in2T = ws + OFF_IN2T;
    float* ctxp = ws + OFF_CTXP;
    float* h2bb = ws + OFF_H2B;
    float* c1a  = ws + OFF_C1;
    float* c2a  = ws + OFF_C2;
    float* attwg = ws + OFF_ATTW;
    float* cumg  = ws + OFF_CUM;
    const float* pm = ws + OFF_PM;

    // ---- one-time: weights -> registers (768 = 24*32, 1536 = 48*32) ----
    float w1[56];
#pragma unroll
    for (int i = 0; i < 56; ++i)
        w1[i] = (i < 24) ? l1k[(size_t)(kq + 32*i)*4096 + col]
                         : l1r[(size_t)(kq + 32*i - 768)*4096 + col];
    float w2[80];
#pragma unroll
    for (int i = 0; i < 80; ++i)
        w2[i] = (i < 48) ? l2k[(size_t)(kq + 32*i)*4096 + col]
                         : l2r[(size_t)(kq + 32*i - 1536)*4096 + col];

    for (int t = 0; t <= TSTEPS + 1; ++t) {
        // ======================= PHASE 1 =======================
        if (t < TSTEPS) {
            // -------- gemv1(t): K=1792 in 2 chunks of 896 rows --------
            float4 acc[8];
#pragma unroll
            for (int q = 0; q < 8; ++q) acc[q] = make_float4(0.f,0.f,0.f,0.f);

            {   // chunk a: rows 0..895 (0..255 bf16 xpre, 256..895 f32)
                const uint4* xps = (const uint4*)((const unsigned short*)(ws + OFF_XPRE) + (size_t)t*8192);
                for (int i = tid; i < 1024; i += 512) {   // 1024 uint4 = 256 rows x 32 b
                    uint4 p = xps[i];
                    int k = i >> 2, b0 = (i & 3)*8;
                    float* d = s_mem + k*36 + b0;
                    d[0] = __uint_as_float(p.x << 16); d[1] = __uint_as_float(p.x & 0xffff0000u);
                    d[2] = __uint_as_float(p.y << 16); d[3] = __uint_as_float(p.y & 0xffff0000u);
                    d[4] = __uint_as_float(p.z << 16); d[5] = __uint_as_float(p.z & 0xffff0000u);
                    d[6] = __uint_as_float(p.w << 16); d[7] = __uint_as_float(p.w & 0xffff0000u);
                }
                const float4* s1 = (const float4*)(ws + OFF_IN1T);
                for (int i = tid; i < 5120; i += 512) {   // rows 256..895
                    int k = 256 + (i >> 3), b0 = (i & 7)*4;
                    *(float4*)(s_mem + k*36 + b0) = s1[i];
                }
            }
            __syncthreads();
#pragma unroll
            for (int i = 0; i < 28; ++i) {
                const float w = w1[i];
                const float* xr = s_mem + (kq + 32*i)*36;
#pragma unroll
                for (int q = 0; q < 8; ++q) {
                    float4 x = *(const float4*)(xr + q*4);
                    acc[q].x = fmaf(w, x.x, acc[q].x); acc[q].y = fmaf(w, x.y, acc[q].y);
                    acc[q].z = fmaf(w, x.z, acc[q].z); acc[q].w = fmaf(w, x.w, acc[q].w);
                }
            }
            __syncthreads();
            {   // chunk b: rows 896..1791 = IN1T rows 640..1535
                const float4* s1 = (const float4*)(ws + OFF_IN1T);
                for (int i = tid; i < 7168; i += 512) {
                    int lr = i >> 3, b0 = (i & 7)*4;
                    *(float4*)(s_mem + lr*36 + b0) = s1[5120 + i];
                }
            }
            __syncthreads();
#pragma unroll
            for (int i = 28; i < 56; ++i) {
                const float w = w1[i];
                const float* xr = s_mem + (kq + 32*(i-28))*36;
#pragma unroll
                for (int q = 0; q < 8; ++q) {
                    float4 x = *(const float4*)(xr + q*4);
                    acc[q].x = fmaf(w, x.x, acc[q].x); acc[q].y = fmaf(w, x.y, acc[q].y);
                    acc[q].z = fmaf(w, x.z, acc[q].z); acc[q].w = fmaf(w, x.w, acc[q].w);
                }
            }
            __syncthreads();
            // butterfly reduce over kq (lanes & 31)
#pragma unroll
            for (int m = 1; m < 32; m <<= 1) {
#pragma unroll
                for (int q = 0; q < 8; ++q) {
                    acc[q].x += __shfl_xor(acc[q].x, m);
                    acc[q].y += __shfl_xor(acc[q].y, m);
                    acc[q].z += __shfl_xor(acc[q].z, m);
                    acc[q].w += __shfl_xor(acc[q].w, m);
                }
            }
            if (kq == 0) {
#pragma unroll
                for (int q = 0; q < 8; ++q) {
                    z1v[(size_t)(q*4+0)*4096 + col] = acc[q].x;
                    z1v[(size_t)(q*4+1)*4096 + col] = acc[q].y;
                    z1v[(size_t)(q*4+2)*4096 + col] = acc[q].z;
                    z1v[(size_t)(q*4+3)*4096 + col] = acc[q].w;
                }
            }
        }
        if (t >= 1 && t <= TSTEPS) {
            // -------- gemv2(t-1): K=2560 in chunks 864/864/832 --------
            float4 acc[8];
#pragma unroll
            for (int q = 0; q < 8; ++q) acc[q] = make_float4(0.f,0.f,0.f,0.f);
            const float4* s2 = (const float4*)in2T;

            {   // chunk c0: rows 0..863
                for (int i = tid; i < 6912; i += 512)
                    *(float4*)(s_mem + (i>>3)*36 + (i&7)*4) = s2[i];
            }
            __syncthreads();
#pragma unroll
            for (int i = 0; i < 27; ++i) {
                const float w = w2[i];
                const float* xr = s_mem + (kq + 32*i)*36;
#pragma unroll
                for (int q = 0; q < 8; ++q) {
                    float4 x = *(const float4*)(xr + q*4);
                    acc[q].x = fmaf(w, x.x, acc[q].x); acc[q].y = fmaf(w, x.y, acc[q].y);
                    acc[q].z = fmaf(w, x.z, acc[q].z); acc[q].w = fmaf(w, x.w, acc[q].w);
                }
            }
            __syncthreads();
            {   // chunk c1: rows 864..1727
                for (int i = tid; i < 6912; i += 512)
                    *(float4*)(s_mem + (i>>3)*36 + (i&7)*4) = s2[6912 + i];
            }
            __syncthreads();
#pragma unroll
            for (int i = 27; i < 54; ++i) {
                const float w = w2[i];
                const float* xr = s_mem + (kq + 32*(i-27))*36;
#pragma unroll
                for (int q = 0; q < 8; ++q) {
                    float4 x = *(const float4*)(xr + q*4);
                    acc[q].x = fmaf(w, x.x, acc[q].x); acc[q].y = fmaf(w, x.y, acc[q].y);
                    acc[q].z = fmaf(w, x.z, acc[q].z); acc[q].w = fmaf(w, x.w, acc[q].w);
                }
            }
            __syncthreads();
            {   // chunk c2: rows 1728..2559
                for (int i = tid; i < 6656; i += 512)
                    *(float4*)(s_mem + (i>>3)*36 + (i&7)*4) = s2[13824 + i];
            }
            __syncthreads();
#pragma unroll
            for (int i = 54; i < 80; ++i) {
                const float w = w2[i];
                const float* xr = s_mem + (kq + 32*(i-54))*36;
#pragma unroll
                for (int q = 0; q < 8; ++q) {
                    float4 x = *(const float4*)(xr + q*4);
                    acc[q].x = fmaf(w, x.x, acc[q].x); acc[q].y = fmaf(w, x.y, acc[q].y);
                    acc[q].z = fmaf(w, x.z, acc[q].z); acc[q].w = fmaf(w, x.w, acc[q].w);
                }
            }
            __syncthreads();
#pragma unroll
            for (int m = 1; m < 32; m <<= 1) {
#pragma unroll
                for (int q = 0; q < 8; ++q) {
                    acc[q].x += __shfl_xor(acc[q].x, m);
                    acc[q].y += __shfl_xor(acc[q].y, m);
                    acc[q].z += __shfl_xor(acc[q].z, m);
                    acc[q].w += __shfl_xor(acc[q].w, m);
                }
            }
            if (kq == 0) {
#pragma unroll
                for (int q = 0; q < 8; ++q) {
                    z2v[(size_t)(q*4+0)*4096 + col] = acc[q].x;
                    z2v[(size_t)(q*4+1)*4096 + col] = acc[q].y;
                    z2v[(size_t)(q*4+2)*4096 + col] = acc[q].z;
                    z2v[(size_t)(q*4+3)*4096 + col] = acc[q].w;
                }
            }
        }
        grid.sync();

        // ======================= PHASE 2 =======================
        {
            float* s_attw = s_mem;          // 200
            float* s_cum  = s_mem + 200;    // 200
            float* s_hid  = s_mem + 400;    // 1024
            float* s_q    = s_mem + 1424;   // 128
            float* s_ex   = s_mem + 1552;   // 200
            float* s_den  = s_mem + 1752;   // 4
            float* s_red  = s_mem + 1756;   // 1024
            float* s_co   = s_mem + 2780;   // 6600

            if (bid < 32) {
                if (t < TSTEPS) {
                    const int b = bid;
                    for (int u = tid; u < 1024; u += 512) {
                        float zi = l1b[u]        + z1v[(size_t)b*4096 + u];
                        float zf = l1b[1024 + u] + z1v[(size_t)b*4096 + 1024 + u];
                        float zg = l1b[2048 + u] + z1v[(size_t)b*4096 + 2048 + u];
                        float zo = l1b[3072 + u] + z1v[(size_t)b*4096 + 3072 + u];
                        float c = sigf(zf)*c1a[b*1024+u] + sigf(zi)*tanhf_(zg);
                        float h = sigf(zo)*tanhf_(c);
                        c1a[b*1024+u] = c;
                        s_hid[u] = h;
                        in1m[(768+u)*32 + b] = h;       // gemv1(t+1)
                        in2T[u*32 + b] = h;             // gemv2(t)
                    }
                    if (tid < 200) { s_attw[tid] = attwg[b*200 + tid]; s_cum[tid] = cumg[b*200 + tid]; }
                    __syncthreads();
                    {   // q partials: 4 k-strips x 128 a
                        int a = tid & 127, kqq = tid >> 7;
                        float s = 0.f;
                        for (int k = kqq*256; k < kqq*256 + 256; ++k)
                            s = fmaf(s_hid[k], wq[k*128 + a], s);
                        s_red[tid] = s;
                    }
                    __syncthreads();
                    if (tid < 128) {
                        float s = s_red[tid] + s_red[128+tid] + s_red[256+tid] + s_red[384+tid];
                        s_q[tid] = tanhf_(s);
                    }
                    for (int idx = tid; idx < 6400; idx += 512) {
                        int tl = idx >> 5, f = idx & 31;
                        float s = 0.f;
                        for (int dw = 0; dw < 31; ++dw) {
                            int tg = tl - 15 + dw;
                            if (tg >= 0 && tg < 200) {
                                s = fmaf(s_attw[tg], lconv[(dw*2+0)*32 + f], s);
                                s = fmaf(s_cum[tg],  lconv[(dw*2+1)*32 + f], s);
                            }
                        }
                        s_co[tl*33 + f] = s;
                    }
                    __syncthreads();
                    if (tid < 400) {
                        int tl = tid >> 1, aq = tid & 1;
                        const float* pmrow = pm + (b*200 + tl)*128;
                        float e = 0.f;
                        for (int a = aq*64; a < aq*64 + 64; ++a) {
                            float s = 0.f;
#pragma unroll
                            for (int f = 0; f < 32; ++f) s = fmaf(s_co[tl*33 + f], ldense[f*128 + a], s);
                            float en = tanhf_(s_q[a] + tanhf_(s) + pmrow[a]);
                            e = fmaf(en, vvec[a], e);
                        }
                        e += __shfl_xor(e, 1, 2);
                        if (aq == 0) s_ex[tl] = __expf(e);
                    }
                    __syncthreads();
                    if (tid < 64) {
                        float s = 0.f;
                        for (int i = tid; i < 200; i += 64) s += s_ex[i];
                        for (int off = 32; off; off >>= 1) s += __shfl_down(s, off, 64);
                        if (tid == 0) s_den[0] = s;
                    }
                    __syncthreads();
                    if (tid < 200) {
                        float w = s_ex[tid] / s_den[0];
                        s_attw[tid] = w;
                        attwg[b*200 + tid] = w;
                        cumg[b*200 + tid] = s_cum[tid] + w;
                        out[OUT_ALIGN + (b*400 + t)*200 + tid] = w;
                    }
                    __syncthreads();
                    {   // context
                        int d = tid;
                        float s = 0.f;
#pragma unroll 8
                        for (int tt = 0; tt < 200; ++tt)
                            s = fmaf(s_attw[tt], mp[(b*200 + tt)*512 + d], s);
                        ctxp[(size_t)(t & 3)*16384 + b*512 + d] = s;
                        in1m[(256 + d)*32 + b] = s;     // gemv1(t+1)
                        in2T[(1024 + d)*32 + b] = s;    // gemv2(t)
                    }
                }
            } else if (bid < 64) {
                if (t >= 1 && t <= TSTEPS) {
                    const int b = bid - 32, t1 = t - 1;
                    float* h2b = h2bb + (size_t)(t1 & 1)*32768;
                    for (int u = tid; u < 1024; u += 512) {
                        float zi = l2b[u]        + z2v[(size_t)b*4096 + u];
                        float zf = l2b[1024 + u] + z2v[(size_t)b*4096 + 1024 + u];
                        float zg = l2b[2048 + u] + z2v[(size_t)b*4096 + 2048 + u];
                        float zo = l2b[3072 + u] + z2v[(size_t)b*4096 + 3072 + u];
                        float c = sigf(zf)*c2a[b*1024+u] + sigf(zi)*tanhf_(zg);
                        float h = sigf(zo)*tanhf_(c);
                        c2a[b*1024+u] = c;
                        in2T[(1536+u)*32 + b] = h;      // gemv2(t)
                        h2b[u*32 + b] = h;              // mel/stop(t-1)
                    }
                }
            } else if (bid < 104) {
                if (t >= 2) {   // mel(t-2): 40 blocks x 2 cols
                    const int t2 = t - 2;
                    const int mc = bid - 64;
                    const int m_l = tid & 1, b = (tid >> 1) & 31, kh = tid >> 6;
                    const int m = mc*2 + m_l;
                    const float* cp  = ctxp + (size_t)((t2 & 3)*32 + b)*512;
                    const float* h2b = h2bb + (size_t)(t2 & 1)*32768;
                    float s = 0.f;
#pragma unroll 4
                    for (int k = kh*192; k < kh*192 + 192; ++k) {
                        float dv = (k < 1024) ? h2b[k*32 + b] : cp[k - 1024];
                        s = fmaf(dv, fw[k*80 + m], s);
                    }
                    s_mem[tid] = s;
                    __syncthreads();
                    if (tid < 64) {
                        float v = 0.f;
#pragma unroll
                        for (int kh2 = 0; kh2 < 8; ++kh2) v += s_mem[kh2*64 + tid];
                        int b2 = tid >> 1, m2 = mc*2 + (tid & 1);
                        out[(b2*80 + m2)*400 + t2] = v + fb[m2];
                    }
                }
            } else if (bid == 104) {
                if (t >= 2) {   // stop(t-2)
                    const int t2 = t - 2;
                    const int b = tid >> 4, kh = tid & 15;
                    const float* cp  = ctxp + (size_t)((t2 & 3)*32 + b)*512;
                    const float* h2b = h2bb + (size_t)(t2 & 1)*32768;
                    float s = 0.f;
#pragma unroll 4
                    for (int k = kh*96; k < kh*96 + 96; ++k) {
                        float dv = (k < 1024) ? h2b[k*32 + b] : cp[k - 1024];
                        s = fmaf(dv, sw[k], s);
                    }
                    s_mem[tid] = s;
                    __syncthreads();
                    if (tid < 32) {
                        float z = 0.f;
#pragma unroll
                        for (int i = 0; i < 16; ++i) z += s_mem[tid*16 + i];
                        out[OUT_GATE + tid*400 + t2] = sigf(z + sb[0]);
                    }
                }
            }
        }
        grid.sync();
    }
}

// ================================================================
// Fallback per-step kernels (Round-5 verified) if coop launch rejected.
// ================================================================
__device__ __forceinline__ void gload_lds16(const float* g, float* l) {
    __builtin_amdgcn_global_load_lds((const __attribute__((address_space(1))) void*)g,
                                     (__attribute__((address_space(3))) void*)l, 16, 0, 0);
}

__global__ void __launch_bounds__(512, 4) kernel_P1(
    const float* __restrict__ l1k, const float* __restrict__ l1r,
    const float* __restrict__ l2k, const float* __restrict__ l2r,
    float* __restrict__ ws, int t)
{
    __shared__ float s_x[10240];
    __shared__ float s_w[8192];
    const int tid = threadIdx.x, bid = blockIdx.x;
    const int jq = tid & 31, bq = tid >> 5;
    const int lane = tid & 63, wid = tid >> 6;
    float4 a0 = make_float4(0.f,0.f,0.f,0.f), a1 = make_float4(0.f,0.f,0.f,0.f);

    if (bid < 224) {
        if (t >= TSTEPS) return;
        const int colgrp = bid & 31, ksp = bid >> 5;
        const int j = colgrp*128 + jq*4;
        const float* wbase = (ksp < 3) ? (l1k + (size_t)ksp*256*4096)
                                       : (l1r + (size_t)(ksp-3)*256*4096);
        const float* gsrc = wbase + colgrp*128 + (lane & 31)*4 + (size_t)(lane >> 5)*4096
                                  + (size_t)(wid*4)*4096;
        float* ldst = s_w + wid*4*128;
        {
            gload_lds16(gsrc,          ldst);
            gload_lds16(gsrc + 2*4096, ldst + 2*128);
        }
        if (ksp == 0) {
            const uint4* src = (const uint4*)((const unsigned short*)(ws + OFF_XPRE) + (size_t)t*8192);
            for (int i = tid; i < 1024; i += 512) {
                uint4 p = src[i];
                float* d = s_x + i*8;
                d[0] = __uint_as_float(p.x << 16); d[1] = __uint_as_float(p.x & 0xffff0000u);
                d[2] = __uint_as_float(p.y << 16); d[3] = __uint_as_float(p.y & 0xffff0000u);
                d[4] = __uint_as_float(p.z << 16); d[5] = __uint_as_float(p.z & 0xffff0000u);
                d[6] = __uint_as_float(p.w << 16); d[7] = __uint_as_float(p.w & 0xffff0000u);
            }
        } else {
            const float4* src = (const float4*)(ws + OFF_IN1T - 8192 + (size_t)ksp*256*32);
            float4* dst = (float4*)s_x;
            for (int i = tid; i < 2048; i += 512) dst[i] = src[i];
        }
        asm volatile("s_waitcnt vmcnt(0)" ::: "memory");
        __syncthreads();
        const float* xb = s_x + bq*2;
        const float* wjb = s_w + jq*4;
        for (int c = 0; c < 8; ++c) {
            if (c + 1 < 8) {
                const float* g = gsrc + (size_t)(c + 1)*32*4096;
                float* lp = ldst + ((c + 1) & 1)*4096;
                gload_lds16(g,          lp);
                gload_lds16(g + 2*4096, lp + 2*128);
            }
            const float* wch = wjb + (c & 1)*4096;
            const float* xch = xb + c*32*32;
#pragma unroll 8
            for (int kk = 0; kk < 32; ++kk) {
                float4 w = *(const float4*)(wch + kk*128);
                float2 x = *(const float2*)(xch + kk*32);
                a0.x = fmaf(x.x, w.x, a0.x); a0.y = fmaf(x.x, w.y, a0.y);
                a0.z = fmaf(x.x, w.z, a0.z); a0.w = fmaf(x.x, w.w, a0.w);
                a1.x = fmaf(x.y, w.x, a1.x); a1.y = fmaf(x.y, w.y, a1.y);
                a1.z = fmaf(x.y, w.z, a1.z); a1.w = fmaf(x.y, w.w, a1.w);
            }
            asm volatile("s_waitcnt vmcnt(0)" ::: "memory");
            __syncthreads();
        }
        float* zp1 = ws + OFF_ZP1;
        *(float4*)(zp1 + (size_t)(ksp*32 + bq*2 + 0)*4096 + j) = a0;
        *(float4*)(zp1 + (size_t)(ksp*32 + bq*2 + 1)*4096 + j) = a1;
    } else {
        if (t < 1 || t > TSTEPS) return;
        const int g2 = bid - 224;
        const int colgrp = g2 & 31, ksp = g2 >> 5;
        const int j = colgrp*128 + jq*4;
        const int kbase = ksp*320;
        float* ldst = s_w + wid*4*128;
        {
            int kg = kbase;
            const float* wb2 = (kg < 1536) ? (l2k + (size_t)kg*4096)
                                           : (l2r + (size_t)(kg - 1536)*4096);
            const float* g = wb2 + colgrp*128 + (lane & 31)*4 + (size_t)(lane >> 5)*4096
                                 + (size_t)(wid*4)*4096;
            gload_lds16(g,          ldst);
            gload_lds16(g + 2*4096, ldst + 2*128);
        }
        {
            const float4* src = (const float4*)(ws + OFF_IN2T + (size_t)kbase*32);
            float4* dst = (float4*)s_x;
            for (int i = tid; i < 2560; i += 512) dst[i] = src[i];
        }
        asm volatile("s_waitcnt vmcnt(0)" ::: "memory");
        __syncthreads();
        const float* xb = s_x + bq*2;
        const float* wjb = s_w + jq*4;
        for (int c = 0; c < 10; ++c) {
            if (c + 1 < 10) {
                int kg = kbase + (c + 1)*32;
                const float* wb2 = (kg < 1536) ? (l2k + (size_t)kg*4096)
                                               : (l2r + (size_t)(kg - 1536)*4096);
                const float* g = wb2 + colgrp*128 + (lane & 31)*4 + (size_t)(lane >> 5)*4096
                                     + (size_t)(wid*4)*4096;
                float* lp = ldst + ((c + 1) & 1)*4096;
                gload_lds16(g,          lp);
                gload_lds16(g + 2*4096, lp + 2*128);
            }
            const float* wch = wjb + (c & 1)*4096;
            const float* xch = xb + c*32*32;
#pragma unroll 8
            for (int kk = 0; kk < 32; ++kk) {
                float4 w = *(const float4*)(wch + kk*128);
                float2 x = *(const float2*)(xch + kk*32);
                a0.x = fmaf(x.x, w.x, a0.x); a0.y = fmaf(x.x, w.y, a0.y);
                a0.z = fmaf(x.x, w.z, a0.z); a0.w = fmaf(x.x, w.w, a0.w);
                a1.x = fmaf(x.y, w.x, a1.x); a1.y = fmaf(x.y, w.y, a1.y);
                a1.z = fmaf(x.y, w.z, a1.z); a1.w = fmaf(x.y, w.w, a1.w);
            }
            asm volatile("s_waitcnt vmcnt(0)" ::: "memory");
            __syncthreads();
        }
        float* zp2 = ws + OFF_ZP2;
        *(float4*)(zp2 + (size_t)(ksp*32 + bq*2 + 0)*4096 + j) = a0;
        *(float4*)(zp2 + (size_t)(ksp*32 + bq*2 + 1)*4096 + j) = a1;
    }
}

__global__ void __launch_bounds__(1024) kernel_P2(
    const float* __restrict__ mp, const float* __restrict__ l1b, const float* __restrict__ l2b,
    const float* __restrict__ wq, const float* __restrict__ vvec,
    const float* __restrict__ lconv, const float* __restrict__ ldense,
    const float* __restrict__ fw, const float* __restrict__ fb,
    const float* __restrict__ sw, const float* __restrict__ sb,
    float* __restrict__ ws, float* __restrict__ out, int t)
{
    __shared__ float s_attw[200], s_cum[200];
    __shared__ float s_hid[1024], s_q[128], s_ex[200], s_den[1];
    __shared__ float s_co[200*33];
    __shared__ float s_red[1024];
    const int tid = threadIdx.x, bid = blockIdx.x;
    float* in1m = ws + OFF_IN1T - 8192;
    float* in2T = ws + OFF_IN2T;
    float* zp1  = ws + OFF_ZP1;
    float* zp2  = ws + OFF_ZP2;
    float* ctxp = ws + OFF_CTXP;
    float* h2bb = ws + OFF_H2B;
    float* c1a  = ws + OFF_C1;
    float* c2a  = ws + OFF_C2;
    float* attw = ws + OFF_ATTW;
    float* cum  = ws + OFF_CUM;
    const float* pm = ws + OFF_PM;

    if (bid < 32) {
        if (t >= TSTEPS) return;
        const int b = bid;
        {
            int u = tid;
            float zi = l1b[u], zf = l1b[1024+u], zg = l1b[2048+u], zo = l1b[3072+u];
#pragma unroll
            for (int kc = 0; kc < KSP1; ++kc) {
                const float* zr = zp1 + (size_t)(kc*32 + b)*4096;
                zi += zr[u]; zf += zr[1024+u]; zg += zr[2048+u]; zo += zr[3072+u];
            }
            float c = sigf(zf)*c1a[b*1024+u] + sigf(zi)*tanhf_(zg);
            float h = sigf(zo)*tanhf_(c);
            c1a[b*1024+u] = c;
            s_hid[u] = h;
            in1m[(768+u)*32 + b] = h;
            in2T[u*32 + b] = h;
        }
        if (tid < 200) { s_attw[tid] = attw[b*200 + tid]; s_cum[tid] = cum[b*200 + tid]; }
        __syncthreads();
        {
            int a = tid & 127, kq = tid >> 7;
            float s = 0.f;
#pragma unroll 8
            for (int k = kq*128; k < kq*128 + 128; ++k)
                s = fmaf(s_hid[k], wq[k*128 + a], s);
            s_red[tid] = s;
        }
        __syncthreads();
        if (tid < 128) {
            float s = 0.f;
#pragma unroll
            for (int q = 0; q < 8; ++q) s += s_red[q*128 + tid];
            s_q[tid] = tanhf_(s);
        }
        for (int idx = tid; idx < 6400; idx += 1024) {
            int tl = idx >> 5, f = idx & 31;
            float s = 0.f;
            for (int dw = 0; dw < 31; ++dw) {
                int tg = tl - 15 + dw;
                if (tg >= 0 && tg < 200) {
                    s = fmaf(s_attw[tg], lconv[(dw*2+0)*32 + f], s);
                    s = fmaf(s_cum[tg],  lconv[(dw*2+1)*32 + f], s);
                }
            }
            s_co[tl*33 + f] = s;
        }
        __syncthreads();
        if (tid < 800) {
            int tl = tid >> 2, aq = tid & 3;
            const float* pmrow = pm + (b*200 + tl)*128;
            float e = 0.f;
#pragma unroll 2
            for (int a = aq*32; a < aq*32 + 32; ++a) {
                float s = 0.f;
#pragma unroll
                for (int f = 0; f < 32; ++f) s = fmaf(s_co[tl*33 + f], ldense[f*128 + a], s);
                float en = tanhf_(s_q[a] + tanhf_(s) + pmrow[a]);
                e = fmaf(en, vvec[a], e);
            }
            e += __shfl_xor(e, 1, 4);
            e += __shfl_xor(e, 2, 4);
            if (aq == 0) s_ex[tl] = __expf(e);
        }
        __syncthreads();
        if (tid < 64) {
            float s = 0.f;
            for (int i = tid; i < 200; i += 64) s += s_ex[i];
            for (int off = 32; off; off >>= 1) s += __shfl_down(s, off, 64);
            if (tid == 0) s_den[0] = s;
        }
        __syncthreads();
        if (tid < 200) {
            float w = s_ex[tid] / s_den[0];
            s_attw[tid] = w;
            attw[b*200 + tid] = w;
            cum[b*200 + tid] = s_cum[tid] + w;
            out[OUT_ALIGN + (b*400 + t)*200 + tid] = w;
        }
        __syncthreads();
        {
            int d = tid & 511, th = tid >> 9;
            float s = 0.f;
#pragma unroll 10
            for (int tt = th*100; tt < th*100 + 100; ++tt)
                s = fmaf(s_attw[tt], mp[(b*200 + tt)*512 + d], s);
            s_red[tid] = s;
        }
        __syncthreads();
        if (tid < 512) {
            float cv = s_red[tid] + s_red[512 + tid];
            ctxp[(size_t)(t & 3)*16384 + b*512 + tid] = cv;
            in1m[(256 + tid)*32 + b] = cv;
            in2T[(1024 + tid)*32 + b] = cv;
        }
    } else if (bid < 64) {
        if (t < 1 || t > TSTEPS) return;
        const int b = bid - 32, t1 = t - 1;
        float* h2b = h2bb + (size_t)(t1 & 1)*32768;
        int u = tid;
        float zi = l2b[u], zf = l2b[1024+u], zg = l2b[2048+u], zo = l2b[3072+u];
#pragma unroll
        for (int kc = 0; kc < KSP2; ++kc) {
            const float* zr = zp2 + (size_t)(kc*32 + b)*4096;
            zi += zr[u]; zf += zr[1024+u]; zg += zr[2048+u]; zo += zr[3072+u];
        }
        float c = sigf(zf)*c2a[b*1024+u] + sigf(zi)*tanhf_(zg);
        float h = sigf(zo)*tanhf_(c);
        c2a[b*1024+u] = c;
        in2T[(1536+u)*32 + b] = h;
        h2b[u*32 + b] = h;
    } else if (bid < 74) {
        if (t < 2) return;
        const int t2 = t - 2;
        const int mc = bid - 64;
        const int m_l = tid & 7, b = (tid >> 3) & 31, kh = tid >> 8;
        const int m = mc*8 + m_l;
        const float* cp = ctxp + (size_t)((t2 & 3)*32 + b)*512;
        const float* h2b = h2bb + (size_t)(t2 & 1)*32768;
        float s = 0.f;
#pragma unroll 8
        for (int k = kh*384; k < kh*384 + 384; ++k) {
            float dv = (k < 1024) ? h2b[k*32 + b] : cp[k - 1024];
            s = fmaf(dv, fw[k*80 + m], s);
        }
        s_red[tid] = s;
        __syncthreads();
        if (tid < 256) {
            float v4 = s_red[tid] + s_red[256+tid] + s_red[512+tid] + s_red[768+tid];
            int b2 = tid >> 3, m2 = mc*8 + (tid & 7);
            out[(b2*80 + m2)*400 + t2] = v4 + fb[m2];
        }
    } else {
        if (t < 2) return;
        const int t2 = t - 2;
        const int b = tid >> 5, kh = tid & 31;
        const float* cp = ctxp + (size_t)((t2 & 3)*32 + b)*512;
        const float* h2b = h2bb + (size_t)(t2 & 1)*32768;
        float s = 0.f;
#pragma unroll 8
        for (int k = kh*48; k < kh*48 + 48; ++k) {
            float dv = (k < 1024) ? h2b[k*32 + b] : cp[k - 1024];
            s = fmaf(dv, sw[k], s);
        }
        s_red[b*32 + kh] = s;
        __syncthreads();
        if (tid < 32) {
            float z = 0.f;
#pragma unroll
            for (int i = 0; i < 32; ++i) z += s_red[tid*32 + i];
            out[OUT_GATE + tid*400 + t2] = sigf(z + sb[0]);
        }
    }
}

extern "C" void kernel_launch(void* const* d_in, const int* in_sizes, int n_in,
                              void* d_out, int out_size, void* d_ws, size_t ws_size,
                              hipStream_t stream) {
    (void)in_sizes; (void)n_in; (void)out_size;
    const float* mp    = (const float*)d_in[0];
    const float* dec   = (const float*)d_in[1];
    const float* pw0   = (const float*)d_in[2];
    const float* pb0   = (const float*)d_in[3];
    const float* pw1   = (const float*)d_in[4];
    const float* pb1   = (const float*)d_in[5];
    const float* l1k   = (const float*)d_in[6];
    const float* l1r   = (const float*)d_in[7];
    const float* l1b   = (const float*)d_in[8];
    const float* l2k   = (const float*)d_in[9];
    const float* l2r   = (const float*)d_in[10];
    const float* l2b   = (const float*)d_in[11];
    const float* wq    = (const float*)d_in[12];
    const float* wm    = (const float*)d_in[13];
    const float* vvec  = (const float*)d_in[14];
    const float* lconv = (const float*)d_in[15];
    const float* ldns  = (const float*)d_in[16];
    const float* fw    = (const float*)d_in[17];
    const float* fb    = (const float*)d_in[18];
    const float* sw    = (const float*)d_in[19];
    const float* sb    = (const float*)d_in[20];
    float* ws  = (float*)d_ws;
    float* out = (float*)d_out;

    if (ws_size < (size_t)WS_FLOATS * sizeof(float)) return;

    prenet_kernel<<<dim3(400, 32), 256, 0, stream>>>(dec, pw0, pb0, pw1, pb1, ws);
    pmem_kernel  <<<dim3(200, 32), 128, 0, stream>>>(mp, wm, ws);
    zero_kernel  <<<256, 256, 0, stream>>>(ws);

    void* kargs[] = {
        (void*)&mp, (void*)&l1k, (void*)&l1r, (void*)&l1b,
        (void*)&l2k, (void*)&l2r, (void*)&l2b,
        (void*)&wq, (void*)&vvec, (void*)&lconv, (void*)&ldns,
        (void*)&fw, (void*)&fb, (void*)&sw, (void*)&sb,
        (void*)&ws, (void*)&out
    };
    hipError_t err = hipLaunchCooperativeKernel((const void*)decoder_kernel,
                                                dim3(256), dim3(512), kargs, 0, stream);
    if (err != hipSuccess) {
        for (int t = 0; t <= TSTEPS; ++t) {
            kernel_P1<<<480, 512, 0, stream>>>(l1k, l1r, l2k, l2r, ws, t);
            kernel_P2<<<75, 1024, 0, stream>>>(mp, l1b, l2b, wq, vvec, lconv, ldns,
                                               fw, fb, sw, sb, ws, out, t);
        }
        kernel_P2<<<75, 1024, 0, stream>>>(mp, l1b, l2b, wq, vvec, lconv, ldns,
                                           fw, fb, sw, sb, ws, out, TSTEPS + 1);
    }
}

// Round 8
// 262037.842 us; speedup vs baseline: 1.0016x; 1.0016x over previous
//
#include <hip/hip_runtime.h>
#include <hip/hip_cooperative_groups.h>
#include <math.h>

namespace cg = cooperative_groups;

// ---------------- problem constants ----------------
#define TSTEPS 400
#define KSP1 7
#define KSP2 8

// ---------------- workspace layout (float offsets) ----------------
#define OFF_XPRE  0u          // prenet out, BF16 [t][k][b]
#define OFF_PM    1638400u    // tanh(memory@wm) fp32 [b][t][128]
#define OFF_IN1T  2457600u    // lstm1 input rows 256..1791, [(k-256)][b]
#define OFF_IN2T  2506752u    // lstm2 input rows [k][b] (2560x32)
#define OFF_ZP1   2588672u    // coop: z1 [b][4096] | fallback: partials [7][32][4096]
#define OFF_ZP2   3506176u    // coop: z2 [b][4096] | fallback: partials [8][32][4096]
#define OFF_CTXP  4554752u    // ctx 4-deep [t&3][b][512]
#define OFF_H2B   4620288u    // h2 2-deep [parity][k][b]
#define OFF_C1    4685824u
#define OFF_C2    4718592u
#define OFF_ATTW  4751360u
#define OFF_CUM   4757760u
#define WS_FLOATS 4764160u

#define OUT_GATE  1024000
#define OUT_ALIGN 1036800

__device__ __forceinline__ float sigf(float x)   { return 1.f / (1.f + __expf(-x)); }
__device__ __forceinline__ float tanhf_(float x) { return 1.f - 2.f / (__expf(2.f*x) + 1.f); }

// ---------------- prologue kernels ----------------
__global__ void __launch_bounds__(256) prenet_kernel(
    const float* __restrict__ dec, const float* __restrict__ w0, const float* __restrict__ b0,
    const float* __restrict__ w1, const float* __restrict__ b1, float* __restrict__ ws)
{
    __shared__ float s_in[80];
    __shared__ float s_h0[256];
    int t = blockIdx.x, b = blockIdx.y, tid = threadIdx.x;
    if (tid < 80) s_in[tid] = (t == 0) ? 0.f : dec[b*32000 + tid*400 + (t-1)];
    __syncthreads();
    float s = b0[tid];
    for (int m = 0; m < 80; ++m) s = fmaf(s_in[m], w0[m*256 + tid], s);
    s_h0[tid] = fmaxf(s, 0.f);
    __syncthreads();
    float s2 = b1[tid];
    for (int k = 0; k < 256; ++k) s2 = fmaf(s_h0[k], w1[k*256 + tid], s2);
    float v = fmaxf(s2, 0.f);
    unsigned u = __float_as_uint(v);
    u += 0x7fffu + ((u >> 16) & 1u);
    ((unsigned short*)(ws + OFF_XPRE))[(size_t)t*8192 + tid*32 + b] = (unsigned short)(u >> 16);
}

__global__ void __launch_bounds__(128) pmem_kernel(
    const float* __restrict__ mp, const float* __restrict__ wm, float* __restrict__ ws)
{
    int t = blockIdx.x, b = blockIdx.y, a = threadIdx.x;
    const float* mrow = mp + (b*200 + t)*512;
    float s = 0.f;
    for (int d = 0; d < 512; ++d) s = fmaf(mrow[d], wm[d*128 + a], s);
    ws[OFF_PM + (b*200 + t)*128 + a] = tanhf_(s);
}

__global__ void __launch_bounds__(256) zero_kernel(float* __restrict__ ws)
{
    int gid = blockIdx.x*256 + threadIdx.x, gsz = gridDim.x*256;
    for (int i = gid; i < 49152; i += gsz) ws[OFF_IN1T + i] = 0.f;
    for (int i = gid; i < 81920; i += gsz) ws[OFF_IN2T + i] = 0.f;
    for (int i = gid; i < 32768; i += gsz) { ws[OFF_C1 + i] = 0.f; ws[OFF_C2 + i] = 0.f; }
    for (int i = gid; i < 65536; i += gsz) { ws[OFF_CTXP + i] = 0.f; ws[OFF_H2B + i] = 0.f; }
    for (int i = gid; i < 6400;  i += gsz) { ws[OFF_ATTW + i] = 0.f; ws[OFF_CUM + i] = 0.f; }
}

// ================================================================
// Persistent cooperative decoder, weights resident in registers.
// 256 blocks x 512 thr, 1 block/CU, <=256 VGPR (launch_bounds 512,2).
// Thread (jl = tid>>5 in [0,16), kq = tid&31): col = bid*16 + jl,
// k in {kq + 32*i}. w1[56] + w2[80] asm-pinned (opaque defs -> the
// register allocator cannot rematerialize the global loads into the
// t-loop; R7 counters proved it did exactly that: VGPR=128, 166MB/step).
// ================================================================
__global__ void __launch_bounds__(512, 2) decoder_kernel(
    const float* __restrict__ mp,
    const float* __restrict__ l1k, const float* __restrict__ l1r, const float* __restrict__ l1b,
    const float* __restrict__ l2k, const float* __restrict__ l2r, const float* __restrict__ l2b,
    const float* __restrict__ wq, const float* __restrict__ vvec,
    const float* __restrict__ lconv, const float* __restrict__ ldense,
    const float* __restrict__ fw, const float* __restrict__ fb,
    const float* __restrict__ sw, const float* __restrict__ sb,
    float* __restrict__ ws, float* __restrict__ out)
{
    cg::grid_group grid = cg::this_grid();
    __shared__ float s_mem[32256];            // 129 KB: x chunks | phase2 scratch
    const int tid = threadIdx.x, bid = blockIdx.x;
    const int jl = tid >> 5, kq = tid & 31;
    const int col = bid*16 + jl;

    float* z1v = ws + OFF_ZP1;                // [b][4096]
    float* z2v = ws + OFF_ZP2;                // [b][4096]
    float* in1m = ws + OFF_IN1T - 8192;       // valid for k >= 256
    float* in2T = ws + OFF_IN2T;
    float* ctxp = ws + OFF_CTXP;
    float* h2bb = ws + OFF_H2B;
    float* c1a  = ws + OFF_C1;
    float* c2a  = ws + OFF_C2;
    float* attwg = ws + OFF_ATTW;
    float* cumg  = ws + OFF_CUM;
    const float* pm = ws + OFF_PM;

    // ---- one-time: weights -> registers (768 = 24*32, 1536 = 48*32) ----
    float w1[56];
#pragma unroll
    for (int i = 0; i < 56; ++i)
        w1[i] = (i < 24) ? l1k[(size_t)(kq + 32*i)*4096 + col]
                         : l1r[(size_t)(kq + 32*i - 768)*4096 + col];
    float w2[80];
#pragma unroll
    for (int i = 0; i < 80; ++i)
        w2[i] = (i < 48) ? l2k[(size_t)(kq + 32*i)*4096 + col]
                         : l2r[(size_t)(kq + 32*i - 1536)*4096 + col];
    // Pin: opaque asm defs -> cannot be rematerialized from global memory.
#pragma unroll
    for (int i = 0; i < 56; ++i) asm volatile("" : "+v"(w1[i]));
#pragma unroll
    for (int i = 0; i < 80; ++i) asm volatile("" : "+v"(w2[i]));

    for (int t = 0; t <= TSTEPS + 1; ++t) {
        // ======================= PHASE 1 =======================
        if (t < TSTEPS) {
            // -------- gemv1(t): K=1792 in 2 chunks of 896 rows --------
            float4 acc[8];
#pragma unroll
            for (int q = 0; q < 8; ++q) acc[q] = make_float4(0.f,0.f,0.f,0.f);

            {   // chunk a: rows 0..895 (0..255 bf16 xpre, 256..895 f32)
                const uint4* xps = (const uint4*)((const unsigned short*)(ws + OFF_XPRE) + (size_t)t*8192);
                for (int i = tid; i < 1024; i += 512) {   // 1024 uint4 = 256 rows x 32 b
                    uint4 p = xps[i];
                    int k = i >> 2, b0 = (i & 3)*8;
                    float* d = s_mem + k*36 + b0;
                    d[0] = __uint_as_float(p.x << 16); d[1] = __uint_as_float(p.x & 0xffff0000u);
                    d[2] = __uint_as_float(p.y << 16); d[3] = __uint_as_float(p.y & 0xffff0000u);
                    d[4] = __uint_as_float(p.z << 16); d[5] = __uint_as_float(p.z & 0xffff0000u);
                    d[6] = __uint_as_float(p.w << 16); d[7] = __uint_as_float(p.w & 0xffff0000u);
                }
                const float4* s1 = (const float4*)(ws + OFF_IN1T);
                for (int i = tid; i < 5120; i += 512) {   // rows 256..895
                    int k = 256 + (i >> 3), b0 = (i & 7)*4;
                    *(float4*)(s_mem + k*36 + b0) = s1[i];
                }
            }
            __syncthreads();
#pragma unroll
            for (int i = 0; i < 28; ++i) {
                const float w = w1[i];
                const float* xr = s_mem + (kq + 32*i)*36;
#pragma unroll
                for (int q = 0; q < 8; ++q) {
                    float4 x = *(const float4*)(xr + q*4);
                    acc[q].x = fmaf(w, x.x, acc[q].x); acc[q].y = fmaf(w, x.y, acc[q].y);
                    acc[q].z = fmaf(w, x.z, acc[q].z); acc[q].w = fmaf(w, x.w, acc[q].w);
                }
            }
            __syncthreads();
            {   // chunk b: rows 896..1791 = IN1T rows 640..1535
                const float4* s1 = (const float4*)(ws + OFF_IN1T);
                for (int i = tid; i < 7168; i += 512) {
                    int lr = i >> 3, b0 = (i & 7)*4;
                    *(float4*)(s_mem + lr*36 + b0) = s1[5120 + i];
                }
            }
            __syncthreads();
#pragma unroll
            for (int i = 28; i < 56; ++i) {
                const float w = w1[i];
                const float* xr = s_mem + (kq + 32*(i-28))*36;
#pragma unroll
                for (int q = 0; q < 8; ++q) {
                    float4 x = *(const float4*)(xr + q*4);
                    acc[q].x = fmaf(w, x.x, acc[q].x); acc[q].y = fmaf(w, x.y, acc[q].y);
                    acc[q].z = fmaf(w, x.z, acc[q].z); acc[q].w = fmaf(w, x.w, acc[q].w);
                }
            }
            __syncthreads();
            // butterfly reduce over kq (lanes & 31)
#pragma unroll
            for (int m = 1; m < 32; m <<= 1) {
#pragma unroll
                for (int q = 0; q < 8; ++q) {
                    acc[q].x += __shfl_xor(acc[q].x, m);
                    acc[q].y += __shfl_xor(acc[q].y, m);
                    acc[q].z += __shfl_xor(acc[q].z, m);
                    acc[q].w += __shfl_xor(acc[q].w, m);
                }
            }
            if (kq == 0) {
#pragma unroll
                for (int q = 0; q < 8; ++q) {
                    z1v[(size_t)(q*4+0)*4096 + col] = acc[q].x;
                    z1v[(size_t)(q*4+1)*4096 + col] = acc[q].y;
                    z1v[(size_t)(q*4+2)*4096 + col] = acc[q].z;
                    z1v[(size_t)(q*4+3)*4096 + col] = acc[q].w;
                }
            }
        }
        if (t >= 1 && t <= TSTEPS) {
            // -------- gemv2(t-1): K=2560 in chunks 864/864/832 --------
            float4 acc[8];
#pragma unroll
            for (int q = 0; q < 8; ++q) acc[q] = make_float4(0.f,0.f,0.f,0.f);
            const float4* s2 = (const float4*)in2T;

            {   // chunk c0: rows 0..863
                for (int i = tid; i < 6912; i += 512)
                    *(float4*)(s_mem + (i>>3)*36 + (i&7)*4) = s2[i];
            }
            __syncthreads();
#pragma unroll
            for (int i = 0; i < 27; ++i) {
                const float w = w2[i];
                const float* xr = s_mem + (kq + 32*i)*36;
#pragma unroll
                for (int q = 0; q < 8; ++q) {
                    float4 x = *(const float4*)(xr + q*4);
                    acc[q].x = fmaf(w, x.x, acc[q].x); acc[q].y = fmaf(w, x.y, acc[q].y);
                    acc[q].z = fmaf(w, x.z, acc[q].z); acc[q].w = fmaf(w, x.w, acc[q].w);
                }
            }
            __syncthreads();
            {   // chunk c1: rows 864..1727
                for (int i = tid; i < 6912; i += 512)
                    *(float4*)(s_mem + (i>>3)*36 + (i&7)*4) = s2[6912 + i];
            }
            __syncthreads();
#pragma unroll
            for (int i = 27; i < 54; ++i) {
                const float w = w2[i];
                const float* xr = s_mem + (kq + 32*(i-27))*36;
#pragma unroll
                for (int q = 0; q < 8; ++q) {
                    float4 x = *(const float4*)(xr + q*4);
                    acc[q].x = fmaf(w, x.x, acc[q].x); acc[q].y = fmaf(w, x.y, acc[q].y);
                    acc[q].z = fmaf(w, x.z, acc[q].z); acc[q].w = fmaf(w, x.w, acc[q].w);
                }
            }
            __syncthreads();
            {   // chunk c2: rows 1728..2559
                for (int i = tid; i < 6656; i += 512)
                    *(float4*)(s_mem + (i>>3)*36 + (i&7)*4) = s2[13824 + i];
            }
            __syncthreads();
#pragma unroll
            for (int i = 54; i < 80; ++i) {
                const float w = w2[i];
                const float* xr = s_mem + (kq + 32*(i-54))*36;
#pragma unroll
                for (int q = 0; q < 8; ++q) {
                    float4 x = *(const float4*)(xr + q*4);
                    acc[q].x = fmaf(w, x.x, acc[q].x); acc[q].y = fmaf(w, x.y, acc[q].y);
                    acc[q].z = fmaf(w, x.z, acc[q].z); acc[q].w = fmaf(w, x.w, acc[q].w);
                }
            }
            __syncthreads();
#pragma unroll
            for (int m = 1; m < 32; m <<= 1) {
#pragma unroll
                for (int q = 0; q < 8; ++q) {
                    acc[q].x += __shfl_xor(acc[q].x, m);
                    acc[q].y += __shfl_xor(acc[q].y, m);
                    acc[q].z += __shfl_xor(acc[q].z, m);
                    acc[q].w += __shfl_xor(acc[q].w, m);
                }
            }
            if (kq == 0) {
#pragma unroll
                for (int q = 0; q < 8; ++q) {
                    z2v[(size_t)(q*4+0)*4096 + col] = acc[q].x;
                    z2v[(size_t)(q*4+1)*4096 + col] = acc[q].y;
                    z2v[(size_t)(q*4+2)*4096 + col] = acc[q].z;
                    z2v[(size_t)(q*4+3)*4096 + col] = acc[q].w;
                }
            }
        }
        grid.sync();

        // ======================= PHASE 2 =======================
        {
            float* s_attw = s_mem;          // 200
            float* s_cum  = s_mem + 200;    // 200
            float* s_hid  = s_mem + 400;    // 1024
            float* s_q    = s_mem + 1424;   // 128
            float* s_ex   = s_mem + 1552;   // 200
            float* s_den  = s_mem + 1752;   // 4
            float* s_red  = s_mem + 1756;   // 1024
            float* s_co   = s_mem + 2780;   // 6600

            if (bid < 32) {
                if (t < TSTEPS) {
                    const int b = bid;
                    for (int u = tid; u < 1024; u += 512) {
                        float zi = l1b[u]        + z1v[(size_t)b*4096 + u];
                        float zf = l1b[1024 + u] + z1v[(size_t)b*4096 + 1024 + u];
                        float zg = l1b[2048 + u] + z1v[(size_t)b*4096 + 2048 + u];
                        float zo = l1b[3072 + u] + z1v[(size_t)b*4096 + 3072 + u];
                        float c = sigf(zf)*c1a[b*1024+u] + sigf(zi)*tanhf_(zg);
                        float h = sigf(zo)*tanhf_(c);
                        c1a[b*1024+u] = c;
                        s_hid[u] = h;
                        in1m[(768+u)*32 + b] = h;       // gemv1(t+1)
                        in2T[u*32 + b] = h;             // gemv2(t)
                    }
                    if (tid < 200) { s_attw[tid] = attwg[b*200 + tid]; s_cum[tid] = cumg[b*200 + tid]; }
                    __syncthreads();
                    {   // q partials: 4 k-strips x 128 a
                        int a = tid & 127, kqq = tid >> 7;
                        float s = 0.f;
                        for (int k = kqq*256; k < kqq*256 + 256; ++k)
                            s = fmaf(s_hid[k], wq[k*128 + a], s);
                        s_red[tid] = s;
                    }
                    __syncthreads();
                    if (tid < 128) {
                        float s = s_red[tid] + s_red[128+tid] + s_red[256+tid] + s_red[384+tid];
                        s_q[tid] = tanhf_(s);
                    }
                    for (int idx = tid; idx < 6400; idx += 512) {
                        int tl = idx >> 5, f = idx & 31;
                        float s = 0.f;
                        for (int dw = 0; dw < 31; ++dw) {
                            int tg = tl - 15 + dw;
                            if (tg >= 0 && tg < 200) {
                                s = fmaf(s_attw[tg], lconv[(dw*2+0)*32 + f], s);
                                s = fmaf(s_cum[tg],  lconv[(dw*2+1)*32 + f], s);
                            }
                        }
                        s_co[tl*33 + f] = s;
                    }
                    __syncthreads();
                    if (tid < 400) {
                        int tl = tid >> 1, aq = tid & 1;
                        const float* pmrow = pm + (b*200 + tl)*128;
                        float e = 0.f;
                        for (int a = aq*64; a < aq*64 + 64; ++a) {
                            float s = 0.f;
#pragma unroll
                            for (int f = 0; f < 32; ++f) s = fmaf(s_co[tl*33 + f], ldense[f*128 + a], s);
                            float en = tanhf_(s_q[a] + tanhf_(s) + pmrow[a]);
                            e = fmaf(en, vvec[a], e);
                        }
                        e += __shfl_xor(e, 1, 2);
                        if (aq == 0) s_ex[tl] = __expf(e);
                    }
                    __syncthreads();
                    if (tid < 64) {
                        float s = 0.f;
                        for (int i = tid; i < 200; i += 64) s += s_ex[i];
                        for (int off = 32; off; off >>= 1) s += __shfl_down(s, off, 64);
                        if (tid == 0) s_den[0] = s;
                    }
                    __syncthreads();
                    if (tid < 200) {
                        float w = s_ex[tid] / s_den[0];
                        s_attw[tid] = w;
                        attwg[b*200 + tid] = w;
                        cumg[b*200 + tid] = s_cum[tid] + w;
                        out[OUT_ALIGN + (b*400 + t)*200 + tid] = w;
                    }
                    __syncthreads();
                    {   // context
                        int d = tid;
                        float s = 0.f;
#pragma unroll 8
                        for (int tt = 0; tt < 200; ++tt)
                            s = fmaf(s_attw[tt], mp[(b*200 + tt)*512 + d], s);
                        ctxp[(size_t)(t & 3)*16384 + b*512 + d] = s;
                        in1m[(256 + d)*32 + b] = s;     // gemv1(t+1)
                        in2T[(1024 + d)*32 + b] = s;    // gemv2(t)
                    }
                }
            } else if (bid < 64) {
                if (t >= 1 && t <= TSTEPS) {
                    const int b = bid - 32, t1 = t - 1;
                    float* h2b = h2bb + (size_t)(t1 & 1)*32768;
                    for (int u = tid; u < 1024; u += 512) {
                        float zi = l2b[u]        + z2v[(size_t)b*4096 + u];
                        float zf = l2b[1024 + u] + z2v[(size_t)b*4096 + 1024 + u];
                        float zg = l2b[2048 + u] + z2v[(size_t)b*4096 + 2048 + u];
                        float zo = l2b[3072 + u] + z2v[(size_t)b*4096 + 3072 + u];
                        float c = sigf(zf)*c2a[b*1024+u] + sigf(zi)*tanhf_(zg);
                        float h = sigf(zo)*tanhf_(c);
                        c2a[b*1024+u] = c;
                        in2T[(1536+u)*32 + b] = h;      // gemv2(t)
                        h2b[u*32 + b] = h;              // mel/stop(t-1)
                    }
                }
            } else if (bid < 104) {
                if (t >= 2) {   // mel(t-2): 40 blocks x 2 cols
                    const int t2 = t - 2;
                    const int mc = bid - 64;
                    const int m_l = tid & 1, b = (tid >> 1) & 31, kh = tid >> 6;
                    const int m = mc*2 + m_l;
                    const float* cp  = ctxp + (size_t)((t2 & 3)*32 + b)*512;
                    const float* h2b = h2bb + (size_t)(t2 & 1)*32768;
                    float s = 0.f;
#pragma unroll 4
                    for (int k = kh*192; k < kh*192 + 192; ++k) {
                        float dv = (k < 1024) ? h2b[k*32 + b] : cp[k - 1024];
                        s = fmaf(dv, fw[k*80 + m], s);
                    }
                    s_mem[tid] = s;
                    __syncthreads();
                    if (tid < 64) {
                        float v = 0.f;
#pragma unroll
                        for (int kh2 = 0; kh2 < 8; ++kh2) v += s_mem[kh2*64 + tid];
                        int b2 = tid >> 1, m2 = mc*2 + (tid & 1);
                        out[(b2*80 + m2)*400 + t2] = v + fb[m2];
                    }
                }
            } else if (bid == 104) {
                if (t >= 2) {   // stop(t-2)
                    const int t2 = t - 2;
                    const int b = tid >> 4, kh = tid & 15;
                    const float* cp  = ctxp + (size_t)((t2 & 3)*32 + b)*512;
                    const float* h2b = h2bb + (size_t)(t2 & 1)*32768;
                    float s = 0.f;
#pragma unroll 4
                    for (int k = kh*96; k < kh*96 + 96; ++k) {
                        float dv = (k < 1024) ? h2b[k*32 + b] : cp[k - 1024];
                        s = fmaf(dv, sw[k], s);
                    }
                    s_mem[tid] = s;
                    __syncthreads();
                    if (tid < 32) {
                        float z = 0.f;
#pragma unroll
                        for (int i = 0; i < 16; ++i) z += s_mem[tid*16 + i];
                        out[OUT_GATE + tid*400 + t2] = sigf(z + sb[0]);
                    }
                }
            }
        }
        grid.sync();
    }
}

// ================================================================
// Fallback per-step kernels (Round-5 verified) if coop launch rejected.
// ================================================================
__device__ __forceinline__ void gload_lds16(const float* g, float* l) {
    __builtin_amdgcn_global_load_lds((const __attribute__((address_space(1))) void*)g,
                                     (__attribute__((address_space(3))) void*)l, 16, 0, 0);
}

__global__ void __launch_bounds__(512, 4) kernel_P1(
    const float* __restrict__ l1k, const float* __restrict__ l1r,
    const float* __restrict__ l2k, const float* __restrict__ l2r,
    float* __restrict__ ws, int t)
{
    __shared__ float s_x[10240];
    __shared__ float s_w[8192];
    const int tid = threadIdx.x, bid = blockIdx.x;
    const int jq = tid & 31, bq = tid >> 5;
    const int lane = tid & 63, wid = tid >> 6;
    float4 a0 = make_float4(0.f,0.f,0.f,0.f), a1 = make_float4(0.f,0.f,0.f,0.f);

    if (bid < 224) {
        if (t >= TSTEPS) return;
        const int colgrp = bid & 31, ksp = bid >> 5;
        const int j = colgrp*128 + jq*4;
        const float* wbase = (ksp < 3) ? (l1k + (size_t)ksp*256*4096)
                                       : (l1r + (size_t)(ksp-3)*256*4096);
        const float* gsrc = wbase + colgrp*128 + (lane & 31)*4 + (size_t)(lane >> 5)*4096
                                  + (size_t)(wid*4)*4096;
        float* ldst = s_w + wid*4*128;
        {
            gload_lds16(gsrc,          ldst);
            gload_lds16(gsrc + 2*4096, ldst + 2*128);
        }
        if (ksp == 0) {
            const uint4* src = (const uint4*)((const unsigned short*)(ws + OFF_XPRE) + (size_t)t*8192);
            for (int i = tid; i < 1024; i += 512) {
                uint4 p = src[i];
                float* d = s_x + i*8;
                d[0] = __uint_as_float(p.x << 16); d[1] = __uint_as_float(p.x & 0xffff0000u);
                d[2] = __uint_as_float(p.y << 16); d[3] = __uint_as_float(p.y & 0xffff0000u);
                d[4] = __uint_as_float(p.z << 16); d[5] = __uint_as_float(p.z & 0xffff0000u);
                d[6] = __uint_as_float(p.w << 16); d[7] = __uint_as_float(p.w & 0xffff0000u);
            }
        } else {
            const float4* src = (const float4*)(ws + OFF_IN1T - 8192 + (size_t)ksp*256*32);
            float4* dst = (float4*)s_x;
            for (int i = tid; i < 2048; i += 512) dst[i] = src[i];
        }
        asm volatile("s_waitcnt vmcnt(0)" ::: "memory");
        __syncthreads();
        const float* xb = s_x + bq*2;
        const float* wjb = s_w + jq*4;
        for (int c = 0; c < 8; ++c) {
            if (c + 1 < 8) {
                const float* g = gsrc + (size_t)(c + 1)*32*4096;
                float* lp = ldst + ((c + 1) & 1)*4096;
                gload_lds16(g,          lp);
                gload_lds16(g + 2*4096, lp + 2*128);
            }
            const float* wch = wjb + (c & 1)*4096;
            const float* xch = xb + c*32*32;
#pragma unroll 8
            for (int kk = 0; kk < 32; ++kk) {
                float4 w = *(const float4*)(wch + kk*128);
                float2 x = *(const float2*)(xch + kk*32);
                a0.x = fmaf(x.x, w.x, a0.x); a0.y = fmaf(x.x, w.y, a0.y);
                a0.z = fmaf(x.x, w.z, a0.z); a0.w = fmaf(x.x, w.w, a0.w);
                a1.x = fmaf(x.y, w.x, a1.x); a1.y = fmaf(x.y, w.y, a1.y);
                a1.z = fmaf(x.y, w.z, a1.z); a1.w = fmaf(x.y, w.w, a1.w);
            }
            asm volatile("s_waitcnt vmcnt(0)" ::: "memory");
            __syncthreads();
        }
        float* zp1 = ws + OFF_ZP1;
        *(float4*)(zp1 + (size_t)(ksp*32 + bq*2 + 0)*4096 + j) = a0;
        *(float4*)(zp1 + (size_t)(ksp*32 + bq*2 + 1)*4096 + j) = a1;
    } else {
        if (t < 1 || t > TSTEPS) return;
        const int g2 = bid - 224;
        const int colgrp = g2 & 31, ksp = g2 >> 5;
        const int j = colgrp*128 + jq*4;
        const int kbase = ksp*320;
        float* ldst = s_w + wid*4*128;
        {
            int kg = kbase;
            const float* wb2 = (kg < 1536) ? (l2k + (size_t)kg*4096)
                                           : (l2r + (size_t)(kg - 1536)*4096);
            const float* g = wb2 + colgrp*128 + (lane & 31)*4 + (size_t)(lane >> 5)*4096
                                 + (size_t)(wid*4)*4096;
            gload_lds16(g,          ldst);
            gload_lds16(g + 2*4096, ldst + 2*128);
        }
        {
            const float4* src = (const float4*)(ws + OFF_IN2T + (size_t)kbase*32);
            float4* dst = (float4*)s_x;
            for (int i = tid; i < 2560; i += 512) dst[i] = src[i];
        }
        asm volatile("s_waitcnt vmcnt(0)" ::: "memory");
        __syncthreads();
        const float* xb = s_x + bq*2;
        const float* wjb = s_w + jq*4;
        for (int c = 0; c < 10; ++c) {
            if (c + 1 < 10) {
                int kg = kbase + (c + 1)*32;
                const float* wb2 = (kg < 1536) ? (l2k + (size_t)kg*4096)
                                               : (l2r + (size_t)(kg - 1536)*4096);
                const float* g = wb2 + colgrp*128 + (lane & 31)*4 + (size_t)(lane >> 5)*4096
                                     + (size_t)(wid*4)*4096;
                float* lp = ldst + ((c + 1) & 1)*4096;
                gload_lds16(g,          lp);
                gload_lds16(g + 2*4096, lp + 2*128);
            }
            const float* wch = wjb + (c & 1)*4096;
            const float* xch = xb + c*32*32;
#pragma unroll 8
            for (int kk = 0; kk < 32; ++kk) {
                float4 w = *(const float4*)(wch + kk*128);
                float2 x = *(const float2*)(xch + kk*32);
                a0.x = fmaf(x.x, w.x, a0.x); a0.y = fmaf(x.x, w.y, a0.y);
                a0.z = fmaf(x.x, w.z, a0.z); a0.w = fmaf(x.x, w.w, a0.w);
                a1.x = fmaf(x.y, w.x, a1.x); a1.y = fmaf(x.y, w.y, a1.y);
                a1.z = fmaf(x.y, w.z, a1.z); a1.w = fmaf(x.y, w.w, a1.w);
            }
            asm volatile("s_waitcnt vmcnt(0)" ::: "memory");
            __syncthreads();
        }
        float* zp2 = ws + OFF_ZP2;
        *(float4*)(zp2 + (size_t)(ksp*32 + bq*2 + 0)*4096 + j) = a0;
        *(float4*)(zp2 + (size_t)(ksp*32 + bq*2 + 1)*4096 + j) = a1;
    }
}

__global__ void __launch_bounds__(1024) kernel_P2(
    const float* __restrict__ mp, const float* __restrict__ l1b, const float* __restrict__ l2b,
    const float* __restrict__ wq, const float* __restrict__ vvec,
    const float* __restrict__ lconv, const float* __restrict__ ldense,
    const float* __restrict__ fw, const float* __restrict__ fb,
    const float* __restrict__ sw, const float* __restrict__ sb,
    float* __restrict__ ws, float* __restrict__ out, int t)
{
    __shared__ float s_attw[200], s_cum[200];
    __shared__ float s_hid[1024], s_q[128], s_ex[200], s_den[1];
    __shared__ float s_co[200*33];
    __shared__ float s_red[1024];
    const int tid = threadIdx.x, bid = blockIdx.x;
    float* in1m = ws + OFF_IN1T - 8192;
    float* in2T = ws + OFF_IN2T;
    float* zp1  = ws + OFF_ZP1;
    float* zp2  = ws + OFF_ZP2;
    float* ctxp = ws + OFF_CTXP;
    float* h2bb = ws + OFF_H2B;
    float* c1a  = ws + OFF_C1;
    float* c2a  = ws + OFF_C2;
    float* attw = ws + OFF_ATTW;
    float* cum  = ws + OFF_CUM;
    const float* pm = ws + OFF_PM;

    if (bid < 32) {
        if (t >= TSTEPS) return;
        const int b = bid;
        {
            int u = tid;
            float zi = l1b[u], zf = l1b[1024+u], zg = l1b[2048+u], zo = l1b[3072+u];
#pragma unroll
            for (int kc = 0; kc < KSP1; ++kc) {
                const float* zr = zp1 + (size_t)(kc*32 + b)*4096;
                zi += zr[u]; zf += zr[1024+u]; zg += zr[2048+u]; zo += zr[3072+u];
            }
            float c = sigf(zf)*c1a[b*1024+u] + sigf(zi)*tanhf_(zg);
            float h = sigf(zo)*tanhf_(c);
            c1a[b*1024+u] = c;
            s_hid[u] = h;
            in1m[(768+u)*32 + b] = h;
            in2T[u*32 + b] = h;
        }
        if (tid < 200) { s_attw[tid] = attw[b*200 + tid]; s_cum[tid] = cum[b*200 + tid]; }
        __syncthreads();
        {
            int a = tid & 127, kq = tid >> 7;
            float s = 0.f;
#pragma unroll 8
            for (int k = kq*128; k < kq*128 + 128; ++k)
                s = fmaf(s_hid[k], wq[k*128 + a], s);
            s_red[tid] = s;
        }
        __syncthreads();
        if (tid < 128) {
            float s = 0.f;
#pragma unroll
            for (int q = 0; q < 8; ++q) s += s_red[q*128 + tid];
            s_q[tid] = tanhf_(s);
        }
        for (int idx = tid; idx < 6400; idx += 1024) {
            int tl = idx >> 5, f = idx & 31;
            float s = 0.f;
            for (int dw = 0; dw < 31; ++dw) {
                int tg = tl - 15 + dw;
                if (tg >= 0 && tg < 200) {
                    s = fmaf(s_attw[tg], lconv[(dw*2+0)*32 + f], s);
                    s = fmaf(s_cum[tg],  lconv[(dw*2+1)*32 + f], s);
                }
            }
            s_co[tl*33 + f] = s;
        }
        __syncthreads();
        if (tid < 800) {
            int tl = tid >> 2, aq = tid & 3;
            const float* pmrow = pm + (b*200 + tl)*128;
            float e = 0.f;
#pragma unroll 2
            for (int a = aq*32; a < aq*32 + 32; ++a) {
                float s = 0.f;
#pragma unroll
                for (int f = 0; f < 32; ++f) s = fmaf(s_co[tl*33 + f], ldense[f*128 + a], s);
                float en = tanhf_(s_q[a] + tanhf_(s) + pmrow[a]);
                e = fmaf(en, vvec[a], e);
            }
            e += __shfl_xor(e, 1, 4);
            e += __shfl_xor(e, 2, 4);
            if (aq == 0) s_ex[tl] = __expf(e);
        }
        __syncthreads();
        if (tid < 64) {
            float s = 0.f;
            for (int i = tid; i < 200; i += 64) s += s_ex[i];
            for (int off = 32; off; off >>= 1) s += __shfl_down(s, off, 64);
            if (tid == 0) s_den[0] = s;
        }
        __syncthreads();
        if (tid < 200) {
            float w = s_ex[tid] / s_den[0];
            s_attw[tid] = w;
            attw[b*200 + tid] = w;
            cum[b*200 + tid] = s_cum[tid] + w;
            out[OUT_ALIGN + (b*400 + t)*200 + tid] = w;
        }
        __syncthreads();
        {
            int d = tid & 511, th = tid >> 9;
            float s = 0.f;
#pragma unroll 10
            for (int tt = th*100; tt < th*100 + 100; ++tt)
                s = fmaf(s_attw[tt], mp[(b*200 + tt)*512 + d], s);
            s_red[tid] = s;
        }
        __syncthreads();
        if (tid < 512) {
            float cv = s_red[tid] + s_red[512 + tid];
            ctxp[(size_t)(t & 3)*16384 + b*512 + tid] = cv;
            in1m[(256 + tid)*32 + b] = cv;
            in2T[(1024 + tid)*32 + b] = cv;
        }
    } else if (bid < 64) {
        if (t < 1 || t > TSTEPS) return;
        const int b = bid - 32, t1 = t - 1;
        float* h2b = h2bb + (size_t)(t1 & 1)*32768;
        int u = tid;
        float zi = l2b[u], zf = l2b[1024+u], zg = l2b[2048+u], zo = l2b[3072+u];
#pragma unroll
        for (int kc = 0; kc < KSP2; ++kc) {
            const float* zr = zp2 + (size_t)(kc*32 + b)*4096;
            zi += zr[u]; zf += zr[1024+u]; zg += zr[2048+u]; zo += zr[3072+u];
        }
        float c = sigf(zf)*c2a[b*1024+u] + sigf(zi)*tanhf_(zg);
        float h = sigf(zo)*tanhf_(c);
        c2a[b*1024+u] = c;
        in2T[(1536+u)*32 + b] = h;
        h2b[u*32 + b] = h;
    } else if (bid < 74) {
        if (t < 2) return;
        const int t2 = t - 2;
        const int mc = bid - 64;
        const int m_l = tid & 7, b = (tid >> 3) & 31, kh = tid >> 8;
        const int m = mc*8 + m_l;
        const float* cp = ctxp + (size_t)((t2 & 3)*32 + b)*512;
        const float* h2b = h2bb + (size_t)(t2 & 1)*32768;
        float s = 0.f;
#pragma unroll 8
        for (int k = kh*384; k < kh*384 + 384; ++k) {
            float dv = (k < 1024) ? h2b[k*32 + b] : cp[k - 1024];
            s = fmaf(dv, fw[k*80 + m], s);
        }
        s_red[tid] = s;
        __syncthreads();
        if (tid < 256) {
            float v4 = s_red[tid] + s_red[256+tid] + s_red[512+tid] + s_red[768+tid];
            int b2 = tid >> 3, m2 = mc*8 + (tid & 7);
            out[(b2*80 + m2)*400 + t2] = v4 + fb[m2];
        }
    } else {
        if (t < 2) return;
        const int t2 = t - 2;
        const int b = tid >> 5, kh = tid & 31;
        const float* cp = ctxp + (size_t)((t2 & 3)*32 + b)*512;
        const float* h2b = h2bb + (size_t)(t2 & 1)*32768;
        float s = 0.f;
#pragma unroll 8
        for (int k = kh*48; k < kh*48 + 48; ++k) {
            float dv = (k < 1024) ? h2b[k*32 + b] : cp[k - 1024];
            s = fmaf(dv, sw[k], s);
        }
        s_red[b*32 + kh] = s;
        __syncthreads();
        if (tid < 32) {
            float z = 0.f;
#pragma unroll
            for (int i = 0; i < 32; ++i) z += s_red[tid*32 + i];
            out[OUT_GATE + tid*400 + t2] = sigf(z + sb[0]);
        }
    }
}

extern "C" void kernel_launch(void* const* d_in, const int* in_sizes, int n_in,
                              void* d_out, int out_size, void* d_ws, size_t ws_size,
                              hipStream_t stream) {
    (void)in_sizes; (void)n_in; (void)out_size;
    const float* mp    = (const float*)d_in[0];
    const float* dec   = (const float*)d_in[1];
    const float* pw0   = (const float*)d_in[2];
    const float* pb0   = (const float*)d_in[3];
    const float* pw1   = (const float*)d_in[4];
    const float* pb1   = (const float*)d_in[5];
    const float* l1k   = (const float*)d_in[6];
    const float* l1r   = (const float*)d_in[7];
    const float* l1b   = (const float*)d_in[8];
    const float* l2k   = (const float*)d_in[9];
    const float* l2r   = (const float*)d_in[10];
    const float* l2b   = (const float*)d_in[11];
    const float* wq    = (const float*)d_in[12];
    const float* wm    = (const float*)d_in[13];
    const float* vvec  = (const float*)d_in[14];
    const float* lconv = (const float*)d_in[15];
    const float* ldns  = (const float*)d_in[16];
    const float* fw    = (const float*)d_in[17];
    const float* fb    = (const float*)d_in[18];
    const float* sw    = (const float*)d_in[19];
    const float* sb    = (const float*)d_in[20];
    float* ws  = (float*)d_ws;
    float* out = (float*)d_out;

    if (ws_size < (size_t)WS_FLOATS * sizeof(float)) return;

    prenet_kernel<<<dim3(400, 32), 256, 0, stream>>>(dec, pw0, pb0, pw1, pb1, ws);
    pmem_kernel  <<<dim3(200, 32), 128, 0, stream>>>(mp, wm, ws);
    zero_kernel  <<<256, 256, 0, stream>>>(ws);

    void* kargs[] = {
        (void*)&mp, (void*)&l1k, (void*)&l1r, (void*)&l1b,
        (void*)&l2k, (void*)&l2r, (void*)&l2b,
        (void*)&wq, (void*)&vvec, (void*)&lconv, (void*)&ldns,
        (void*)&fw, (void*)&fb, (void*)&sw, (void*)&sb,
        (void*)&ws, (void*)&out
    };
    hipError_t err = hipLaunchCooperativeKernel((const void*)decoder_kernel,
                                                dim3(256), dim3(512), kargs, 0, stream);
    if (err != hipSuccess) {
        for (int t = 0; t <= TSTEPS; ++t) {
            kernel_P1<<<480, 512, 0, stream>>>(l1k, l1r, l2k, l2r, ws, t);
            kernel_P2<<<75, 1024, 0, stream>>>(mp, l1b, l2b, wq, vvec, lconv, ldns,
                                               fw, fb, sw, sb, ws, out, t);
        }
        kernel_P2<<<75, 1024, 0, stream>>>(mp, l1b, l2b, wq, vvec, lconv, ldns,
                                           fw, fb, sw, sb, ws, out, TSTEPS + 1);
    }
}